// Round 14
// baseline (73.224 us; speedup 1.0000x reference)
//
#include <hip/hip_runtime.h>

#define Dq    256
#define ATTR  400
#define HW    3136
#define NB    32
#define PXT   64      // pixel tile per block
#define NTILE 49      // HW/PXT

typedef __attribute__((ext_vector_type(8))) short bf16x8;
typedef __attribute__((ext_vector_type(4))) float f32x4;

__device__ __forceinline__ unsigned short f2bf(float f) {
  unsigned int x = __float_as_uint(f);
  return (unsigned short)((x + 0x7FFFu + ((x >> 16) & 1u)) >> 16);
}

// direct global->LDS async copy, 16B per lane, zero VGPR round-trip
__device__ __forceinline__ void g2lds16(const float* g, float* l) {
  __builtin_amdgcn_global_load_lds(
      (const __attribute__((address_space(1))) unsigned int*)g,
      (__attribute__((address_space(3))) unsigned int*)l,
      16, 0, 0);
}

// ---------------- Kernel A: per-batch count-sketch vector sk1[b][256] ----------------
__global__ __launch_bounds__(256) void k_sk1(
    const float* __restrict__ oh, const float* __restrict__ W_emb,
    const float* __restrict__ b_emb, const float* __restrict__ conv_w,
    const float* __restrict__ conv_b, const int* __restrict__ h1,
    const float* __restrict__ s1, float* __restrict__ sk1_out) {
  __shared__ float ohs[ATTR];
  __shared__ float ts[Dq];
  __shared__ float sk[Dq];
  const int b = blockIdx.x, tid = threadIdx.x;
  for (int j = tid; j < ATTR; j += 256) ohs[j] = oh[b * ATTR + j];
  sk[tid] = 0.f;
  __syncthreads();
  float acc = b_emb[tid];
  const float* wr = W_emb + tid * ATTR;
  for (int j = 0; j < ATTR; ++j) acc = fmaf(ohs[j], wr[j], acc);
  ts[tid] = acc;
  __syncthreads();
  float a = conv_b[tid];
  const float* cr = conv_w + tid * Dq;
  for (int k = 0; k < Dq; ++k) a = fmaf(ts[k], cr[k], a);
  atomicAdd(&sk[h1[tid]], a * s1[tid]);
  __syncthreads();
  sk1_out[b * Dq + tid] = sk[tid];
}

// ---------------- Kernel B: circular conv + scatter into MFMA A-fragment layout ----------------
// A[m=o][k=c] = G[b][c][o] = s2[c] * T[o,h2[c]]:
//   frag = (o>>4)*8 + (c>>5), lane = (o&15) | (((c>>3)&3)<<4), j = c&7.
__global__ __launch_bounds__(256) void k_G(
    const float* __restrict__ sk1, const float* __restrict__ conv1_w,
    const int* __restrict__ h2, const float* __restrict__ s2,
    unsigned short* __restrict__ Abuf) {
  __shared__ float sks[Dq];
  __shared__ float w1[Dq];
  __shared__ float Tl[Dq];
  const int b = blockIdx.x >> 5, o = blockIdx.x & 31, c = threadIdx.x;
  sks[c] = sk1[b * Dq + c];
  w1[c]  = conv1_w[o * Dq + c];
  __syncthreads();
  float t = 0.f;
  for (int d = 0; d < Dq; ++d) t = fmaf(w1[d], sks[(d - c) & 255], t);
  Tl[c] = t;
  __syncthreads();
  const float g = s2[c] * Tl[h2[c]];
  const int frag = (o >> 4) * 8 + (c >> 5);
  const int lane = (o & 15) | (((c >> 3) & 3) << 4);
  Abuf[(((size_t)b * 16 + frag) * 64 + lane) * 8 + (c & 7)] = f2bf(g);
}

// ---------------- Kernel TILE v2: global_load_lds stage -> MFMA gate -> store ----------------
// Block = 256 thr (4 waves), tile [256 ch][64 px] f32 LINEAR in LDS (64 KB).
// Stage: wave w issues 16 fire-and-forget global_load_lds (1 KB each, covers
// channels [w*64,(w+1)*64)); 16 KB in flight per wave with ZERO data VGPRs.
// Gate: wave w = px subtile [w*16,(w+1)*16); f32 column gather from LDS
// (4-way bank aliasing, short phase), relu+cvt, MFMA vs Abuf (L2-resident).
// Store: ds_read_b128 rows (2-way = free), s4 multiply, 256B-segment f32x4
// global stores. Entity touched exactly once in global memory, full f32
// precision for the feature product.
__global__ __launch_bounds__(256) void k_tile(
    const float* __restrict__ ent,            // [B,256,HW]
    const unsigned short* __restrict__ Abuf,  // [B,16,64,8]
    const float* __restrict__ c1b, const float* __restrict__ c2w,
    const float* __restrict__ c2b,
    float* __restrict__ out)                  // map [B,HW] then feat [B,256,HW]
{
  __shared__ float tile[Dq * PXT];            // 65536 B, linear [c][64]
  __shared__ float s_lds[PXT];
  const int b = blockIdx.y;
  const int px_base = blockIdx.x * PXT;       // 49*64 = 3136 exact
  const int t = threadIdx.x;
  const int w = t >> 6, l = t & 63;

  const float* eb = ent + (size_t)b * Dq * HW + px_base;

  // ---- stage: 16 async 1KB copies per wave; lane l -> c=cb+l/16, px=4*(l%16) ----
#pragma unroll
  for (int i = 0; i < 16; ++i) {
    const int cb = w * 64 + i * 4;
    const float* src = eb + (size_t)(cb + (l >> 4)) * HW + 4 * (l & 15);
    g2lds16(src, &tile[cb * PXT]);
  }
  asm volatile("s_waitcnt vmcnt(0)");
  __syncthreads();

  // ---- gate: wave w owns px subtile [w*16, w*16+16) ----
  const int n = l & 15, kg = l >> 4;
  const unsigned short* Ab = Abuf + ((size_t)b * 16 * 64 + l) * 8;

  f32x4 acc0 = {0.f, 0.f, 0.f, 0.f}, acc1 = {0.f, 0.f, 0.f, 0.f};
#pragma unroll
  for (int ks = 0; ks < 8; ++ks) {
    bf16x8 bv;
#pragma unroll
    for (int j = 0; j < 8; ++j) {
      const float fv = tile[(ks * 32 + kg * 8 + j) * PXT + w * 16 + n];
      bv[j] = (short)f2bf(fmaxf(fv, 0.f));
    }
    bf16x8 a0 = *reinterpret_cast<const bf16x8*>(Ab + (size_t)(0 * 8 + ks) * 64 * 8);
    bf16x8 a1 = *reinterpret_cast<const bf16x8*>(Ab + (size_t)(1 * 8 + ks) * 64 * 8);
    acc0 = __builtin_amdgcn_mfma_f32_16x16x32_bf16(a0, bv, acc0, 0, 0, 0);
    acc1 = __builtin_amdgcn_mfma_f32_16x16x32_bf16(a1, bv, acc1, 0, 0, 0);
  }

  // epilogue: C/D col(px)=l&15, row(o)=kg*4+reg (+16 tile1)
  const float4 b1a = reinterpret_cast<const float4*>(c1b)[kg];
  const float4 b1b = reinterpret_cast<const float4*>(c1b)[kg + 4];
  const float4 w2a = reinterpret_cast<const float4*>(c2w)[kg];
  const float4 w2b = reinterpret_cast<const float4*>(c2w)[kg + 4];
  float z = 0.f;
  z = fmaf(w2a.x, fmaxf(acc0[0] + b1a.x, 0.f), z);
  z = fmaf(w2a.y, fmaxf(acc0[1] + b1a.y, 0.f), z);
  z = fmaf(w2a.z, fmaxf(acc0[2] + b1a.z, 0.f), z);
  z = fmaf(w2a.w, fmaxf(acc0[3] + b1a.w, 0.f), z);
  z = fmaf(w2b.x, fmaxf(acc1[0] + b1b.x, 0.f), z);
  z = fmaf(w2b.y, fmaxf(acc1[1] + b1b.y, 0.f), z);
  z = fmaf(w2b.z, fmaxf(acc1[2] + b1b.z, 0.f), z);
  z = fmaf(w2b.w, fmaxf(acc1[3] + b1b.w, 0.f), z);
  z += __shfl_xor(z, 16);
  z += __shfl_xor(z, 32);
  const float s = 1.f / (1.f + __expf(-(z + c2b[0])));
  if (l < 16) {
    out[(size_t)b * HW + px_base + w * 16 + l] = s;
    s_lds[w * 16 + l] = s;
  }
  __syncthreads();

  // ---- store: feat = s * e (f32), ds_read_b128 + 256B-segment f32x4 stores ----
  const f32x4 s4v = *reinterpret_cast<const f32x4*>(&s_lds[(t & 15) * 4]);
  float* fb = out + (size_t)NB * HW + (size_t)b * Dq * HW + px_base;
#pragma unroll
  for (int k = 0; k < 16; ++k) {
    const int c = k * 16 + (t >> 4);
    f32x4 e = *reinterpret_cast<const f32x4*>(&tile[c * PXT + (t & 15) * 4]);
    *reinterpret_cast<f32x4*>(fb + (size_t)c * HW + (t & 15) * 4) = e * s4v;
  }
}

extern "C" void kernel_launch(void* const* d_in, const int* in_sizes, int n_in,
                              void* d_out, int out_size, void* d_ws, size_t ws_size,
                              hipStream_t stream) {
  const float* ent    = (const float*)d_in[0];
  const float* oh     = (const float*)d_in[1];
  const float* W_emb  = (const float*)d_in[2];
  const float* b_emb  = (const float*)d_in[3];
  const float* conv_w = (const float*)d_in[4];
  const float* conv_b = (const float*)d_in[5];
  const float* c1w    = (const float*)d_in[6];
  const float* c1b    = (const float*)d_in[7];
  const float* c2w    = (const float*)d_in[8];
  const float* c2b    = (const float*)d_in[9];
  const int*   h1     = (const int*)d_in[10];
  const int*   h2     = (const int*)d_in[11];
  const float* s1     = (const float*)d_in[12];
  const float* s2     = (const float*)d_in[13];

  float* ws  = (float*)d_ws;
  float* sk1 = ws;                                        // 32*256 f32
  unsigned short* Abuf = (unsigned short*)(ws + NB * Dq); // 32*16*64*8 bf16

  hipLaunchKernelGGL(k_sk1, dim3(NB), dim3(256), 0, stream,
                     oh, W_emb, b_emb, conv_w, conv_b, h1, s1, sk1);
  hipLaunchKernelGGL(k_G, dim3(NB * 32), dim3(256), 0, stream,
                     sk1, c1w, h2, s2, Abuf);
  hipLaunchKernelGGL(k_tile, dim3(NTILE, NB), dim3(256), 0, stream,
                     ent, Abuf, c1b, c2w, c2b, (float*)d_out);
}